// Round 16
// baseline (182.835 us; speedup 1.0000x reference)
//
#include <hip/hip_runtime.h>
#include <hip/hip_bf16.h>

// ---- types ----
typedef short bf16x8 __attribute__((ext_vector_type(8)));          // 8 bf16 = 4 VGPRs (MFMA A/B frag)
typedef unsigned short u16x8 __attribute__((ext_vector_type(8)));
typedef unsigned short u16x4 __attribute__((ext_vector_type(4)));
typedef float f32x4 __attribute__((ext_vector_type(4)));           // MFMA C/D frag

typedef unsigned int __attribute__((address_space(1))) gu32;       // global
typedef unsigned int __attribute__((address_space(3))) lu32;       // LDS

#define MFMA16(a, b, c) __builtin_amdgcn_mfma_f32_16x16x32_bf16((a), (b), (c), 0, 0, 0)

constexpr int SEQ = 2048;
constexpr int NH = 16;
constexpr int NTOK = 2 * SEQ;  // 4096

__device__ __forceinline__ float bf2f(unsigned short u) {
  union { unsigned int i; float f; } v; v.i = ((unsigned int)u) << 16; return v.f;
}
__device__ __forceinline__ unsigned short f2bf(float f) {
  __hip_bfloat16 h = __float2bfloat16(f);   // RNE
  return __builtin_bit_cast(unsigned short, h);
}
// pack two fp32 -> bf16 pair by TRUNCATION via one v_perm_b32 (hi<<16 | lo)
__device__ __forceinline__ unsigned int pkbf_trunc(float hi, float lo) {
  return __builtin_amdgcn_perm(__builtin_bit_cast(unsigned int, hi),
                               __builtin_bit_cast(unsigned int, lo), 0x07060302u);
}
__device__ __forceinline__ u16x8 cvt8(const float* __restrict__ p) {
  f32x4 a = *(const f32x4*)p;
  f32x4 b = *(const f32x4*)(p + 4);
  u16x8 r;
#pragma unroll
  for (int j = 0; j < 4; j++) { r[j] = f2bf(a[j]); r[4 + j] = f2bf(b[j]); }
  return r;
}

// =====================================================================
// Convert pass: x (4M) and Wq/Wk/Wv/Wo (1M each) fp32 -> bf16 into ws.
// (~13 µs, at its 72 MB memory roofline — frozen)
// =====================================================================
__global__ __launch_bounds__(256) void cvt_all(
    const float* __restrict__ x, const float* __restrict__ wq, const float* __restrict__ wk,
    const float* __restrict__ wv, const float* __restrict__ wo,
    unsigned short* __restrict__ Xb, unsigned short* __restrict__ Wb) {
  const int z = blockIdx.y;
  const float* src = (z == 0) ? x : (z == 1) ? wq : (z == 2) ? wk : (z == 3) ? wv : wo;
  unsigned short* dst = (z == 0) ? Xb : Wb + (size_t)(z - 1) * 1024 * 1024;
  const int n = (z == 0) ? NTOK * 1024 : 1024 * 1024;
  for (int i = (blockIdx.x * 256 + threadIdx.x) * 8; i < n; i += gridDim.x * 256 * 8)
    *(u16x8*)(dst + i) = cvt8(src + i);
}

// =====================================================================
// Async global->LDS staging with XOR-chunk permutation (verified r3):
// 16B chunk (row, c8) -> slot row*8 + (c8 ^ (row&7)).
// =====================================================================
template <int ROWS, int NWAVE>
__device__ __forceinline__ void stage_glds(const unsigned short* __restrict__ gbase,
                                           int rstride,
                                           unsigned short* __restrict__ lds,
                                           int wid, int lane) {
  constexpr int ISS = ROWS * 8 / (NWAVE * 64);
#pragma unroll
  for (int t = 0; t < ISS; ++t) {
    const int slot = (wid * ISS + t) * 64 + lane;
    const int row = slot >> 3;
    const int c8 = (slot & 7) ^ (row & 7);
    const unsigned short* gp = gbase + (size_t)row * rstride + c8 * 8;
    unsigned short* lp = lds + (size_t)(wid * ISS + t) * 512;   // wave-uniform, 1 KiB/issue
    __builtin_amdgcn_global_load_lds((const gu32*)gp, (lu32*)lp, 16, 0, 0);
  }
}

__device__ __forceinline__ bf16x8 frag_ld(const unsigned short* __restrict__ lds, int row, int c8) {
  const int slot = row * 8 + (c8 ^ (row & 7));
  return *(const bf16x8*)(lds + slot * 8);
}

// =====================================================================
// m97-style bf16 GEMM, XCD-local grid (verified r10): m0 from blockIdx.x
// (fastest dim) so blocks sharing A-rows co-locate on an XCD.
// r16: 64x64 tiles — acc VGPRs halve -> ~7-8 waves/SIMD resident
// (occupancy law: r5/r10-vs-r13/r12/r15 all showed waves/CU beats
// per-wave MFMA:staging ratio for these latency-bound kernels).
// =====================================================================
template <int BM, int BN, int LDC, bool CF32>
__global__ __launch_bounds__(256) void gemm_lds(
    const unsigned short* __restrict__ A,   // [M][1024] bf16 row-major
    const unsigned short* __restrict__ B,   // [LDC][1024] bf16 (nn.Linear weight rows)
    void* __restrict__ Cv) {
  constexpr int K = 1024;
  constexpr int MI = BM / 32, NI = BN / 32;

  __shared__ __align__(16) unsigned short As[BM * 64];
  __shared__ __align__(16) unsigned short Bs[BN * 64];

  const int tid = threadIdx.x;
  const int wid = tid >> 6;
  const int lane = tid & 63;
  const int quad = lane >> 4;
  const int c16 = lane & 15;
  const int wrow = wid >> 1, wcol = wid & 1;

  const int m0 = blockIdx.x * BM;   // m fastest -> same-A blocks share an XCD
  const int n0 = blockIdx.y * BN;

  f32x4 acc[MI][NI];
#pragma unroll
  for (int i = 0; i < MI; i++)
#pragma unroll
    for (int j = 0; j < NI; j++) acc[i][j] = f32x4{0.f, 0.f, 0.f, 0.f};

  for (int kb = 0; kb < K; kb += 64) {
    __syncthreads();
    stage_glds<BM, 4>(A + (size_t)m0 * K + kb, K, As, wid, lane);
    stage_glds<BN, 4>(B + (size_t)n0 * K + kb, K, Bs, wid, lane);
    __syncthreads();
#pragma unroll
    for (int ks = 0; ks < 2; ++ks) {
      bf16x8 af[MI], bfr[NI];
#pragma unroll
      for (int i = 0; i < MI; i++)
        af[i] = frag_ld(As, wrow * (BM / 2) + i * 16 + c16, ks * 4 + quad);
#pragma unroll
      for (int j = 0; j < NI; j++)
        bfr[j] = frag_ld(Bs, wcol * (BN / 2) + j * 16 + c16, ks * 4 + quad);
#pragma unroll
      for (int i = 0; i < MI; i++)
#pragma unroll
        for (int j = 0; j < NI; j++) acc[i][j] = MFMA16(af[i], bfr[j], acc[i][j]);
    }
  }

#pragma unroll
  for (int i = 0; i < MI; i++) {
#pragma unroll
    for (int j = 0; j < NI; j++) {
      int row = m0 + wrow * (BM / 2) + i * 16 + quad * 4;
      int col = n0 + wcol * (BN / 2) + j * 16 + c16;
#pragma unroll
      for (int r = 0; r < 4; r++) {
        if constexpr (CF32) ((float*)Cv)[(size_t)(row + r) * LDC + col] = acc[i][j][r];
        else ((unsigned short*)Cv)[(size_t)(row + r) * LDC + col] = f2bf(acc[i][j][r]);
      }
    }
  }
}

// =====================================================================
// Flash attention v10 (causal) — r15's proven kernel (42 µs), frozen.
// Single Vt buffer, LDS 33.8 KB -> 4 blocks/CU; backfill grid
// (NH, 2, 32), long tiles first, K/V XCD-local (FETCH 12 MB).
// =====================================================================
__device__ __forceinline__ int vt_idx(int d, int kv) {
  int ck = kv >> 3;
  int s = ((d >> 3) ^ d) & 7;
  return d * 64 + ((ck ^ s) << 3) + (kv & 7);
}

struct AttnShared {
  unsigned short Kt[2][64 * 64];   // XOR-chunk swizzled K rows (8 KB x2)
  unsigned short Vt[64 * 64];      // vt_idx-swizzled V^T (8 KB, single buffer)
  unsigned short Pt[4][16 * 72];   // per-wave P^T rows [q=c16][kv], stride 72 (9 KB)
};

__global__ __launch_bounds__(256) void attn_kernel(
    const unsigned short* __restrict__ QKV,   // [NTOK][3072]: Q | K | V (bf16)
    unsigned short* __restrict__ Oa) {        // [NTOK][1024] bf16
  __shared__ AttnShared sh;
  const int h = blockIdx.x;
  const int b = blockIdx.y;
  const int t = 31 - blockIdx.z;   // long tiles first (z is slowest dim)
  const int tid = threadIdx.x;
  const int wid = tid >> 6, lane = tid & 63;
  const int quad = lane >> 4, c16 = lane & 15;
  const size_t tokbase = (size_t)b * SEQ;
  const int q0 = t * 64;
  const int nkv = t + 1;

  // Q fragments (B-operand), scaled by 0.125 * log2(e)
  const unsigned short* qp = QKV + (tokbase + q0 + wid * 16 + c16) * 3072 + h * 64;
  bf16x8 qf[2];
#pragma unroll
  for (int ks = 0; ks < 2; ++ks) {
    u16x8 u = *(const u16x8*)(qp + ks * 32 + quad * 8);
    bf16x8 tq;
#pragma unroll
    for (int j = 0; j < 8; j++) tq[j] = (short)f2bf(0.1803368801f * bf2f(u[j]));
    qf[ks] = tq;
  }

  const unsigned short* kbase = QKV + tokbase * 3072 + 1024 + h * 64;
  const unsigned short* vbase = QKV + tokbase * 3072 + 2048 + h * 64;
  const int vkv = (tid >> 4) * 4;   // V stager: 4 kv rows
  const int vd = (tid & 15) * 4;    //           4 d cols

  f32x4 o[4];
  float lacc = 0.f;
#pragma unroll
  for (int nt = 0; nt < 4; nt++) o[nt] = f32x4{0.f, 0.f, 0.f, 0.f};
  unsigned short* PtW = sh.Pt[wid];

  // preload tile 0
  stage_glds<64, 4>(kbase, 3072, sh.Kt[0], wid, lane);
  u16x4 vr[4];
#pragma unroll
  for (int i = 0; i < 4; i++)
    vr[i] = *(const u16x4*)(vbase + (size_t)(vkv + i) * 3072 + vd);

  for (int kt = 0; kt < nkv; ++kt) {
    const int buf = kt & 1;
    __syncthreads();   // prior iter's PV reads of Vt (and Pt use) complete
    // write prefetched V regs -> Vt (single buffer): pack kv-pairs, 4x ds_write_b64
#pragma unroll
    for (int dd = 0; dd < 4; ++dd) {
      uint2 w;
      w.x = (unsigned int)vr[0][dd] | ((unsigned int)vr[1][dd] << 16);
      w.y = (unsigned int)vr[2][dd] | ((unsigned int)vr[3][dd] << 16);
      *(uint2*)&sh.Vt[vt_idx(vd + dd, vkv)] = w;
    }
    __syncthreads();   // Vt visible; drains vmcnt -> Kt[buf] glds complete

    if (kt + 1 < nkv) {  // prefetch next tile (after barrier -> flies over compute)
      const size_t nofs = (size_t)(kt + 1) * 64;
      stage_glds<64, 4>(kbase + nofs * 3072, 3072, sh.Kt[buf ^ 1], wid, lane);
#pragma unroll
      for (int i = 0; i < 4; i++)
        vr[i] = *(const u16x4*)(vbase + (nofs + vkv + i) * 3072 + vd);
    }

    // ---- S^T = K (Q*scale*log2e)^T - 16 : lane holds (kv=nt*16+quad*4+r, q=c16) ----
    const unsigned short* KtB = sh.Kt[buf];
    f32x4 st[4];
#pragma unroll
    for (int nt = 0; nt < 4; ++nt) {
      f32x4 a = f32x4{-16.f, -16.f, -16.f, -16.f};
      a = MFMA16(frag_ld(KtB, nt * 16 + c16, quad), qf[0], a);
      a = MFMA16(frag_ld(KtB, nt * 16 + c16, 4 + quad), qf[1], a);
      st[nt] = a;
    }
    if (kt == nkv - 1) {   // diagonal kv-tile
      const int kv0 = kt * 64;
      const int qg = q0 + wid * 16 + c16;
#pragma unroll
      for (int nt = 0; nt < 4; nt++)
#pragma unroll
        for (int r = 0; r < 4; r++) {
          int kg = kv0 + nt * 16 + quad * 4 + r;
          if (kg > qg) st[nt][r] = -1e30f;
        }
    }

    // ---- p = exp2(s) [bare v_exp_f32]; v_perm trunc-pack; 4x ds_write_b64 ----
#pragma unroll
    for (int nt = 0; nt < 4; nt++) {
      float p0 = __builtin_amdgcn_exp2f(st[nt][0]);
      float p1 = __builtin_amdgcn_exp2f(st[nt][1]);
      float p2 = __builtin_amdgcn_exp2f(st[nt][2]);
      float p3 = __builtin_amdgcn_exp2f(st[nt][3]);
      lacc += (p0 + p1) + (p2 + p3);
      uint2 w;
      w.x = pkbf_trunc(p1, p0);
      w.y = pkbf_trunc(p3, p2);
      *(uint2*)&PtW[c16 * 72 + nt * 16 + quad * 4] = w;
    }

    // ---- O^T += V^T P^T (wave-private Pt_T; lgkmcnt-ordered, no barrier) ----
#pragma unroll
    for (int ks = 0; ks < 2; ++ks) {
      bf16x8 pf = *(const bf16x8*)&PtW[c16 * 72 + ks * 32 + quad * 8];
#pragma unroll
      for (int nt2 = 0; nt2 < 4; ++nt2) {
        bf16x8 vf = *(const bf16x8*)&sh.Vt[vt_idx(nt2 * 16 + c16, ks * 32 + quad * 8)];
        o[nt2] = MFMA16(vf, pf, o[nt2]);
      }
    }
  }

  // ---- epilogue: l across quads (2 shuffles); packed dwordx2 stores ----
  lacc += __shfl_xor(lacc, 16);
  lacc += __shfl_xor(lacc, 32);
  const float linv = 1.f / lacc;
  const size_t row = tokbase + q0 + wid * 16 + c16;
#pragma unroll
  for (int nt2 = 0; nt2 < 4; nt2++) {
    uint2 w;
    w.x = (unsigned int)f2bf(o[nt2][0] * linv) | ((unsigned int)f2bf(o[nt2][1] * linv) << 16);
    w.y = (unsigned int)f2bf(o[nt2][2] * linv) | ((unsigned int)f2bf(o[nt2][3] * linv) << 16);
    *(uint2*)&Oa[row * 1024 + h * 64 + nt2 * 16 + quad * 4] = w;
  }
}

// =====================================================================
// Round-2 fallback GEMM (fp32 staging) — used only if ws_size < 40 MB.
// =====================================================================
template <int BM, int BN, int LDC, bool AF32, bool CF32>
__global__ __launch_bounds__(256) void gemm_bt(
    const void* __restrict__ Av, const float* __restrict__ W0, const float* __restrict__ W1,
    const float* __restrict__ W2, void* __restrict__ Cv) {
  constexpr int K = 1024;
  constexpr int LDS_LD = 72;
  constexpr int MI = BM / 32, NI = BN / 32;
  __shared__ __align__(16) unsigned short As[BM][LDS_LD];
  __shared__ __align__(16) unsigned short Bs[BN][LDS_LD];
  const int tid = threadIdx.x, wid = tid >> 6, lane = tid & 63;
  const int quad = lane >> 4, c16 = lane & 15;
  const int wrow = wid >> 1, wcol = wid & 1;
  const float* W = (blockIdx.z == 0) ? W0 : (blockIdx.z == 1 ? W1 : W2);
  const int m0 = blockIdx.y * BM, n0 = blockIdx.x * BN, cofs = blockIdx.z * 1024;
  f32x4 acc[MI][NI];
#pragma unroll
  for (int i = 0; i < MI; i++)
#pragma unroll
    for (int j = 0; j < NI; j++) acc[i][j] = f32x4{0.f, 0.f, 0.f, 0.f};
  for (int kb = 0; kb < K; kb += 64) {
    __syncthreads();
#pragma unroll
    for (int c = tid; c < BM * 8; c += 256) {
      int row = c >> 3, c8 = c & 7;
      if constexpr (AF32)
        *(u16x8*)&As[row][c8 * 8] = cvt8((const float*)Av + (size_t)(m0 + row) * K + kb + c8 * 8);
      else
        *(u16x8*)&As[row][c8 * 8] = *(const u16x8*)((const unsigned short*)Av + (size_t)(m0 + row) * K + kb + c8 * 8);
    }
#pragma unroll
    for (int c = tid; c < BN * 8; c += 256) {
      int row = c >> 3, c8 = c & 7;
      *(u16x8*)&Bs[row][c8 * 8] = cvt8(W + (size_t)(n0 + row) * K + kb + c8 * 8);
    }
    __syncthreads();
#pragma unroll
    for (int ks = 0; ks < 2; ++ks) {
      bf16x8 af[MI], bfr[NI];
#pragma unroll
      for (int i = 0; i < MI; i++)
        af[i] = *(const bf16x8*)&As[wrow * (BM / 2) + i * 16 + c16][ks * 32 + quad * 8];
#pragma unroll
      for (int j = 0; j < NI; j++)
        bfr[j] = *(const bf16x8*)&Bs[wcol * (BN / 2) + j * 16 + c16][ks * 32 + quad * 8];
#pragma unroll
      for (int i = 0; i < MI; i++)
#pragma unroll
        for (int j = 0; j < NI; j++) acc[i][j] = MFMA16(af[i], bfr[j], acc[i][j]);
    }
  }
#pragma unroll
  for (int i = 0; i < MI; i++)
#pragma unroll
    for (int j = 0; j < NI; j++) {
      int row = m0 + wrow * (BM / 2) + i * 16 + quad * 4;
      int col = n0 + wcol * (BN / 2) + j * 16 + c16 + cofs;
#pragma unroll
      for (int r = 0; r < 4; r++) {
        if constexpr (CF32) ((float*)Cv)[(size_t)(row + r) * LDC + col] = acc[i][j][r];
        else ((unsigned short*)Cv)[(size_t)(row + r) * LDC + col] = f2bf(acc[i][j][r]);
      }
    }
}

// =====================================================================
extern "C" void kernel_launch(void* const* d_in, const int* in_sizes, int n_in,
                              void* d_out, int out_size, void* d_ws, size_t ws_size,
                              hipStream_t stream) {
  const float* x = (const float*)d_in[0];
  const float* Wq = (const float*)d_in[2];
  const float* Wk = (const float*)d_in[3];
  const float* Wv = (const float*)d_in[4];
  const float* Wo = (const float*)d_in[5];
  float* out = (float*)d_out;

  unsigned short* QKV = (unsigned short*)d_ws;                 // [4096][3072] bf16 (24MB)
  unsigned short* Wb = QKV + (size_t)NTOK * 3072;              // 4 x [1024][1024] bf16 (8MB)
  unsigned short* Xb = Wb + (size_t)4 * 1024 * 1024;           // [4096][1024] bf16 (8MB), == AT
  unsigned short* AT = Xb;

  if (ws_size >= (size_t)40 * 1024 * 1024) {
    cvt_all<<<dim3(256, 5), 256, 0, stream>>>(x, Wq, Wk, Wv, Wo, Xb, Wb);
    // fused QKV projection: 64x64 tiles, 3072 blocks -> ~8 blocks/CU; XCD-local
    gemm_lds<64, 64, 3072, false><<<dim3(64, 48), 256, 0, stream>>>(Xb, Wb, QKV);
    // flash attention (r15, 42 µs proven)
    attn_kernel<<<dim3(NH, 2, 32), 256, 0, stream>>>(QKV, AT);
    // output projection: 64x64 tiles, 1024 blocks -> 4+/CU; XCD-local
    gemm_lds<64, 64, 1024, true><<<dim3(64, 16), 256, 0, stream>>>(
        AT, Wb + (size_t)3 * 1024 * 1024, out);
  } else {
    unsigned short* QKV2 = (unsigned short*)d_ws;
    unsigned short* AT2 = QKV2 + (size_t)NTOK * 3072;
    gemm_bt<128, 128, 3072, true, false><<<dim3(8, 32, 3), 256, 0, stream>>>(x, Wq, Wk, Wv, QKV2);
    attn_kernel<<<dim3(NH, 2, 32), 256, 0, stream>>>(QKV2, AT2);
    gemm_bt<64, 64, 1024, false, true><<<dim3(16, 64, 1), 256, 0, stream>>>(AT2, Wo, Wo, Wo, out);
  }
}

// Round 17
// 175.717 us; speedup vs baseline: 1.0405x; 1.0405x over previous
//
#include <hip/hip_runtime.h>
#include <hip/hip_bf16.h>

// ---- types ----
typedef short bf16x8 __attribute__((ext_vector_type(8)));          // 8 bf16 = 4 VGPRs (MFMA A/B frag)
typedef unsigned short u16x8 __attribute__((ext_vector_type(8)));
typedef unsigned short u16x4 __attribute__((ext_vector_type(4)));
typedef float f32x4 __attribute__((ext_vector_type(4)));           // MFMA C/D frag

typedef unsigned int __attribute__((address_space(1))) gu32;       // global
typedef unsigned int __attribute__((address_space(3))) lu32;       // LDS

#define MFMA16(a, b, c) __builtin_amdgcn_mfma_f32_16x16x32_bf16((a), (b), (c), 0, 0, 0)

constexpr int SEQ = 2048;
constexpr int NH = 16;
constexpr int NTOK = 2 * SEQ;  // 4096

__device__ __forceinline__ float bf2f(unsigned short u) {
  union { unsigned int i; float f; } v; v.i = ((unsigned int)u) << 16; return v.f;
}
__device__ __forceinline__ unsigned short f2bf(float f) {
  __hip_bfloat16 h = __float2bfloat16(f);   // RNE
  return __builtin_bit_cast(unsigned short, h);
}
// pack two fp32 -> bf16 pair by TRUNCATION via one v_perm_b32 (hi<<16 | lo)
__device__ __forceinline__ unsigned int pkbf_trunc(float hi, float lo) {
  return __builtin_amdgcn_perm(__builtin_bit_cast(unsigned int, hi),
                               __builtin_bit_cast(unsigned int, lo), 0x07060302u);
}
__device__ __forceinline__ u16x8 cvt8(const float* __restrict__ p) {
  f32x4 a = *(const f32x4*)p;
  f32x4 b = *(const f32x4*)(p + 4);
  u16x8 r;
#pragma unroll
  for (int j = 0; j < 4; j++) { r[j] = f2bf(a[j]); r[4 + j] = f2bf(b[j]); }
  return r;
}

// =====================================================================
// Convert pass: x (4M) and Wq/Wk/Wv/Wo (1M each) fp32 -> bf16 into ws.
// (~13 µs, at its 72 MB memory roofline — frozen)
// =====================================================================
__global__ __launch_bounds__(256) void cvt_all(
    const float* __restrict__ x, const float* __restrict__ wq, const float* __restrict__ wk,
    const float* __restrict__ wv, const float* __restrict__ wo,
    unsigned short* __restrict__ Xb, unsigned short* __restrict__ Wb) {
  const int z = blockIdx.y;
  const float* src = (z == 0) ? x : (z == 1) ? wq : (z == 2) ? wk : (z == 3) ? wv : wo;
  unsigned short* dst = (z == 0) ? Xb : Wb + (size_t)(z - 1) * 1024 * 1024;
  const int n = (z == 0) ? NTOK * 1024 : 1024 * 1024;
  for (int i = (blockIdx.x * 256 + threadIdx.x) * 8; i < n; i += gridDim.x * 256 * 8)
    *(u16x8*)(dst + i) = cvt8(src + i);
}

// =====================================================================
// Async global->LDS staging with XOR-chunk permutation (verified r3):
// 16B chunk (row, c8) -> slot row*8 + (c8 ^ (row&7)).
// =====================================================================
template <int ROWS, int NWAVE>
__device__ __forceinline__ void stage_glds(const unsigned short* __restrict__ gbase,
                                           int rstride,
                                           unsigned short* __restrict__ lds,
                                           int wid, int lane) {
  constexpr int ISS = ROWS * 8 / (NWAVE * 64);
#pragma unroll
  for (int t = 0; t < ISS; ++t) {
    const int slot = (wid * ISS + t) * 64 + lane;
    const int row = slot >> 3;
    const int c8 = (slot & 7) ^ (row & 7);
    const unsigned short* gp = gbase + (size_t)row * rstride + c8 * 8;
    unsigned short* lp = lds + (size_t)(wid * ISS + t) * 512;   // wave-uniform, 1 KiB/issue
    __builtin_amdgcn_global_load_lds((const gu32*)gp, (lu32*)lp, 16, 0, 0);
  }
}

__device__ __forceinline__ bf16x8 frag_ld(const unsigned short* __restrict__ lds, int row, int c8) {
  const int slot = row * 8 + (c8 ^ (row & 7));
  return *(const bf16x8*)(lds + slot * 8);
}

// =====================================================================
// m97-style bf16 GEMM, XCD-local grid (verified r10): m0 from blockIdx.x
// (fastest dim) so blocks sharing A-rows co-locate on an XCD.
// Tile shape bracketed by measurement: 128x128 too few waves (r13/r14),
// 64x64 too much staging (r16) -> 128x64 is the optimum at K=1024.
// =====================================================================
template <int BM, int BN, int LDC, bool CF32>
__global__ __launch_bounds__(256) void gemm_lds(
    const unsigned short* __restrict__ A,   // [M][1024] bf16 row-major
    const unsigned short* __restrict__ B,   // [LDC][1024] bf16 (nn.Linear weight rows)
    void* __restrict__ Cv) {
  constexpr int K = 1024;
  constexpr int MI = BM / 32, NI = BN / 32;

  __shared__ __align__(16) unsigned short As[BM * 64];
  __shared__ __align__(16) unsigned short Bs[BN * 64];

  const int tid = threadIdx.x;
  const int wid = tid >> 6;
  const int lane = tid & 63;
  const int quad = lane >> 4;
  const int c16 = lane & 15;
  const int wrow = wid >> 1, wcol = wid & 1;

  const int m0 = blockIdx.x * BM;   // m fastest -> same-A blocks share an XCD
  const int n0 = blockIdx.y * BN;

  f32x4 acc[MI][NI];
#pragma unroll
  for (int i = 0; i < MI; i++)
#pragma unroll
    for (int j = 0; j < NI; j++) acc[i][j] = f32x4{0.f, 0.f, 0.f, 0.f};

  for (int kb = 0; kb < K; kb += 64) {
    __syncthreads();
    stage_glds<BM, 4>(A + (size_t)m0 * K + kb, K, As, wid, lane);
    stage_glds<BN, 4>(B + (size_t)n0 * K + kb, K, Bs, wid, lane);
    __syncthreads();
#pragma unroll
    for (int ks = 0; ks < 2; ++ks) {
      bf16x8 af[MI], bfr[NI];
#pragma unroll
      for (int i = 0; i < MI; i++)
        af[i] = frag_ld(As, wrow * (BM / 2) + i * 16 + c16, ks * 4 + quad);
#pragma unroll
      for (int j = 0; j < NI; j++)
        bfr[j] = frag_ld(Bs, wcol * (BN / 2) + j * 16 + c16, ks * 4 + quad);
#pragma unroll
      for (int i = 0; i < MI; i++)
#pragma unroll
        for (int j = 0; j < NI; j++) acc[i][j] = MFMA16(af[i], bfr[j], acc[i][j]);
    }
  }

#pragma unroll
  for (int i = 0; i < MI; i++) {
#pragma unroll
    for (int j = 0; j < NI; j++) {
      int row = m0 + wrow * (BM / 2) + i * 16 + quad * 4;
      int col = n0 + wcol * (BN / 2) + j * 16 + c16;
#pragma unroll
      for (int r = 0; r < 4; r++) {
        if constexpr (CF32) ((float*)Cv)[(size_t)(row + r) * LDC + col] = acc[i][j][r];
        else ((unsigned short*)Cv)[(size_t)(row + r) * LDC + col] = f2bf(acc[i][j][r]);
      }
    }
  }
}

// =====================================================================
// Flash attention v10 (causal) — r15's proven kernel (42 µs), frozen.
// Single Vt buffer, LDS 33.8 KB -> 4 blocks/CU; backfill grid
// (NH, 2, 32), long tiles first, K/V XCD-local (FETCH 12 MB).
// =====================================================================
__device__ __forceinline__ int vt_idx(int d, int kv) {
  int ck = kv >> 3;
  int s = ((d >> 3) ^ d) & 7;
  return d * 64 + ((ck ^ s) << 3) + (kv & 7);
}

struct AttnShared {
  unsigned short Kt[2][64 * 64];   // XOR-chunk swizzled K rows (8 KB x2)
  unsigned short Vt[64 * 64];      // vt_idx-swizzled V^T (8 KB, single buffer)
  unsigned short Pt[4][16 * 72];   // per-wave P^T rows [q=c16][kv], stride 72 (9 KB)
};

__global__ __launch_bounds__(256) void attn_kernel(
    const unsigned short* __restrict__ QKV,   // [NTOK][3072]: Q | K | V (bf16)
    unsigned short* __restrict__ Oa) {        // [NTOK][1024] bf16
  __shared__ AttnShared sh;
  const int h = blockIdx.x;
  const int b = blockIdx.y;
  const int t = 31 - blockIdx.z;   // long tiles first (z is slowest dim)
  const int tid = threadIdx.x;
  const int wid = tid >> 6, lane = tid & 63;
  const int quad = lane >> 4, c16 = lane & 15;
  const size_t tokbase = (size_t)b * SEQ;
  const int q0 = t * 64;
  const int nkv = t + 1;

  // Q fragments (B-operand), scaled by 0.125 * log2(e)
  const unsigned short* qp = QKV + (tokbase + q0 + wid * 16 + c16) * 3072 + h * 64;
  bf16x8 qf[2];
#pragma unroll
  for (int ks = 0; ks < 2; ++ks) {
    u16x8 u = *(const u16x8*)(qp + ks * 32 + quad * 8);
    bf16x8 tq;
#pragma unroll
    for (int j = 0; j < 8; j++) tq[j] = (short)f2bf(0.1803368801f * bf2f(u[j]));
    qf[ks] = tq;
  }

  const unsigned short* kbase = QKV + tokbase * 3072 + 1024 + h * 64;
  const unsigned short* vbase = QKV + tokbase * 3072 + 2048 + h * 64;
  const int vkv = (tid >> 4) * 4;   // V stager: 4 kv rows
  const int vd = (tid & 15) * 4;    //           4 d cols

  f32x4 o[4];
  float lacc = 0.f;
#pragma unroll
  for (int nt = 0; nt < 4; nt++) o[nt] = f32x4{0.f, 0.f, 0.f, 0.f};
  unsigned short* PtW = sh.Pt[wid];

  // preload tile 0
  stage_glds<64, 4>(kbase, 3072, sh.Kt[0], wid, lane);
  u16x4 vr[4];
#pragma unroll
  for (int i = 0; i < 4; i++)
    vr[i] = *(const u16x4*)(vbase + (size_t)(vkv + i) * 3072 + vd);

  for (int kt = 0; kt < nkv; ++kt) {
    const int buf = kt & 1;
    __syncthreads();   // prior iter's PV reads of Vt (and Pt use) complete
    // write prefetched V regs -> Vt (single buffer): pack kv-pairs, 4x ds_write_b64
#pragma unroll
    for (int dd = 0; dd < 4; ++dd) {
      uint2 w;
      w.x = (unsigned int)vr[0][dd] | ((unsigned int)vr[1][dd] << 16);
      w.y = (unsigned int)vr[2][dd] | ((unsigned int)vr[3][dd] << 16);
      *(uint2*)&sh.Vt[vt_idx(vd + dd, vkv)] = w;
    }
    __syncthreads();   // Vt visible; drains vmcnt -> Kt[buf] glds complete

    if (kt + 1 < nkv) {  // prefetch next tile (after barrier -> flies over compute)
      const size_t nofs = (size_t)(kt + 1) * 64;
      stage_glds<64, 4>(kbase + nofs * 3072, 3072, sh.Kt[buf ^ 1], wid, lane);
#pragma unroll
      for (int i = 0; i < 4; i++)
        vr[i] = *(const u16x4*)(vbase + (nofs + vkv + i) * 3072 + vd);
    }

    // ---- S^T = K (Q*scale*log2e)^T - 16 : lane holds (kv=nt*16+quad*4+r, q=c16) ----
    const unsigned short* KtB = sh.Kt[buf];
    f32x4 st[4];
#pragma unroll
    for (int nt = 0; nt < 4; ++nt) {
      f32x4 a = f32x4{-16.f, -16.f, -16.f, -16.f};
      a = MFMA16(frag_ld(KtB, nt * 16 + c16, quad), qf[0], a);
      a = MFMA16(frag_ld(KtB, nt * 16 + c16, 4 + quad), qf[1], a);
      st[nt] = a;
    }
    if (kt == nkv - 1) {   // diagonal kv-tile
      const int kv0 = kt * 64;
      const int qg = q0 + wid * 16 + c16;
#pragma unroll
      for (int nt = 0; nt < 4; nt++)
#pragma unroll
        for (int r = 0; r < 4; r++) {
          int kg = kv0 + nt * 16 + quad * 4 + r;
          if (kg > qg) st[nt][r] = -1e30f;
        }
    }

    // ---- p = exp2(s) [bare v_exp_f32]; v_perm trunc-pack; 4x ds_write_b64 ----
#pragma unroll
    for (int nt = 0; nt < 4; nt++) {
      float p0 = __builtin_amdgcn_exp2f(st[nt][0]);
      float p1 = __builtin_amdgcn_exp2f(st[nt][1]);
      float p2 = __builtin_amdgcn_exp2f(st[nt][2]);
      float p3 = __builtin_amdgcn_exp2f(st[nt][3]);
      lacc += (p0 + p1) + (p2 + p3);
      uint2 w;
      w.x = pkbf_trunc(p1, p0);
      w.y = pkbf_trunc(p3, p2);
      *(uint2*)&PtW[c16 * 72 + nt * 16 + quad * 4] = w;
    }

    // ---- O^T += V^T P^T (wave-private Pt_T; lgkmcnt-ordered, no barrier) ----
#pragma unroll
    for (int ks = 0; ks < 2; ++ks) {
      bf16x8 pf = *(const bf16x8*)&PtW[c16 * 72 + ks * 32 + quad * 8];
#pragma unroll
      for (int nt2 = 0; nt2 < 4; ++nt2) {
        bf16x8 vf = *(const bf16x8*)&sh.Vt[vt_idx(nt2 * 16 + c16, ks * 32 + quad * 8)];
        o[nt2] = MFMA16(vf, pf, o[nt2]);
      }
    }
  }

  // ---- epilogue: l across quads (2 shuffles); packed dwordx2 stores ----
  lacc += __shfl_xor(lacc, 16);
  lacc += __shfl_xor(lacc, 32);
  const float linv = 1.f / lacc;
  const size_t row = tokbase + q0 + wid * 16 + c16;
#pragma unroll
  for (int nt2 = 0; nt2 < 4; nt2++) {
    uint2 w;
    w.x = (unsigned int)f2bf(o[nt2][0] * linv) | ((unsigned int)f2bf(o[nt2][1] * linv) << 16);
    w.y = (unsigned int)f2bf(o[nt2][2] * linv) | ((unsigned int)f2bf(o[nt2][3] * linv) << 16);
    *(uint2*)&Oa[row * 1024 + h * 64 + nt2 * 16 + quad * 4] = w;
  }
}

// =====================================================================
// Round-2 fallback GEMM (fp32 staging) — used only if ws_size < 40 MB.
// =====================================================================
template <int BM, int BN, int LDC, bool AF32, bool CF32>
__global__ __launch_bounds__(256) void gemm_bt(
    const void* __restrict__ Av, const float* __restrict__ W0, const float* __restrict__ W1,
    const float* __restrict__ W2, void* __restrict__ Cv) {
  constexpr int K = 1024;
  constexpr int LDS_LD = 72;
  constexpr int MI = BM / 32, NI = BN / 32;
  __shared__ __align__(16) unsigned short As[BM][LDS_LD];
  __shared__ __align__(16) unsigned short Bs[BN][LDS_LD];
  const int tid = threadIdx.x, wid = tid >> 6, lane = tid & 63;
  const int quad = lane >> 4, c16 = lane & 15;
  const int wrow = wid >> 1, wcol = wid & 1;
  const float* W = (blockIdx.z == 0) ? W0 : (blockIdx.z == 1 ? W1 : W2);
  const int m0 = blockIdx.y * BM, n0 = blockIdx.x * BN, cofs = blockIdx.z * 1024;
  f32x4 acc[MI][NI];
#pragma unroll
  for (int i = 0; i < MI; i++)
#pragma unroll
    for (int j = 0; j < NI; j++) acc[i][j] = f32x4{0.f, 0.f, 0.f, 0.f};
  for (int kb = 0; kb < K; kb += 64) {
    __syncthreads();
#pragma unroll
    for (int c = tid; c < BM * 8; c += 256) {
      int row = c >> 3, c8 = c & 7;
      if constexpr (AF32)
        *(u16x8*)&As[row][c8 * 8] = cvt8((const float*)Av + (size_t)(m0 + row) * K + kb + c8 * 8);
      else
        *(u16x8*)&As[row][c8 * 8] = *(const u16x8*)((const unsigned short*)Av + (size_t)(m0 + row) * K + kb + c8 * 8);
    }
#pragma unroll
    for (int c = tid; c < BN * 8; c += 256) {
      int row = c >> 3, c8 = c & 7;
      *(u16x8*)&Bs[row][c8 * 8] = cvt8(W + (size_t)(n0 + row) * K + kb + c8 * 8);
    }
    __syncthreads();
#pragma unroll
    for (int ks = 0; ks < 2; ++ks) {
      bf16x8 af[MI], bfr[NI];
#pragma unroll
      for (int i = 0; i < MI; i++)
        af[i] = *(const bf16x8*)&As[wrow * (BM / 2) + i * 16 + c16][ks * 32 + quad * 8];
#pragma unroll
      for (int j = 0; j < NI; j++)
        bfr[j] = *(const bf16x8*)&Bs[wcol * (BN / 2) + j * 16 + c16][ks * 32 + quad * 8];
#pragma unroll
      for (int i = 0; i < MI; i++)
#pragma unroll
        for (int j = 0; j < NI; j++) acc[i][j] = MFMA16(af[i], bfr[j], acc[i][j]);
    }
  }
#pragma unroll
  for (int i = 0; i < MI; i++)
#pragma unroll
    for (int j = 0; j < NI; j++) {
      int row = m0 + wrow * (BM / 2) + i * 16 + quad * 4;
      int col = n0 + wcol * (BN / 2) + j * 16 + c16 + cofs;
#pragma unroll
      for (int r = 0; r < 4; r++) {
        if constexpr (CF32) ((float*)Cv)[(size_t)(row + r) * LDC + col] = acc[i][j][r];
        else ((unsigned short*)Cv)[(size_t)(row + r) * LDC + col] = f2bf(acc[i][j][r]);
      }
    }
}

// =====================================================================
extern "C" void kernel_launch(void* const* d_in, const int* in_sizes, int n_in,
                              void* d_out, int out_size, void* d_ws, size_t ws_size,
                              hipStream_t stream) {
  const float* x = (const float*)d_in[0];
  const float* Wq = (const float*)d_in[2];
  const float* Wk = (const float*)d_in[3];
  const float* Wv = (const float*)d_in[4];
  const float* Wo = (const float*)d_in[5];
  float* out = (float*)d_out;

  unsigned short* QKV = (unsigned short*)d_ws;                 // [4096][3072] bf16 (24MB)
  unsigned short* Wb = QKV + (size_t)NTOK * 3072;              // 4 x [1024][1024] bf16 (8MB)
  unsigned short* Xb = Wb + (size_t)4 * 1024 * 1024;           // [4096][1024] bf16 (8MB), == AT
  unsigned short* AT = Xb;

  if (ws_size >= (size_t)40 * 1024 * 1024) {
    cvt_all<<<dim3(256, 5), 256, 0, stream>>>(x, Wq, Wk, Wv, Wo, Xb, Wb);
    // fused QKV projection: 128x64 tiles, 1536 blocks = 5/CU resident; XCD-local
    gemm_lds<128, 64, 3072, false><<<dim3(32, 48), 256, 0, stream>>>(Xb, Wb, QKV);
    // flash attention (r15, 42 µs proven)
    attn_kernel<<<dim3(NH, 2, 32), 256, 0, stream>>>(QKV, AT);
    // output projection: 128x64 tiles, 512 blocks = 2/CU (r10/r15 proven shape)
    gemm_lds<128, 64, 1024, true><<<dim3(32, 16), 256, 0, stream>>>(
        AT, Wb + (size_t)3 * 1024 * 1024, out);
  } else {
    unsigned short* QKV2 = (unsigned short*)d_ws;
    unsigned short* AT2 = QKV2 + (size_t)NTOK * 3072;
    gemm_bt<128, 128, 3072, true, false><<<dim3(8, 32, 3), 256, 0, stream>>>(x, Wq, Wk, Wv, QKV2);
    attn_kernel<<<dim3(NH, 2, 32), 256, 0, stream>>>(QKV2, AT2);
    gemm_bt<64, 64, 1024, false, true><<<dim3(16, 64, 1), 256, 0, stream>>>(AT2, Wo, Wo, Wo, out);
  }
}